// Round 1
// baseline (260.171 us; speedup 1.0000x reference)
//
#include <hip/hip_runtime.h>

// Problem constants (fixed by setup_inputs): B=2, C=24, D=H=W=96.
static constexpr int   kS = 96 * 96 * 96;   // 884736 spatial positions per batch
static constexpr int   kC = 24;
static constexpr int   kB = 2;
static constexpr int   kN = kB * kS;        // 1769472 total positions
static constexpr float kSmooth = 1e-5f;

// d_out is re-poisoned to 0xAA before every timed launch -> zero it ourselves.
__global__ void init_out_kernel(float* out) { out[0] = 0.0f; }

__global__ __launch_bounds__(256) void mce_kernel(
    const float* __restrict__ logit0,
    const int*   __restrict__ target,
    const int*   __restrict__ cfb,      // class_for_batch, 12 ints
    float*       __restrict__ out)
{
    // Build the present-class bitmask (wave-uniform; compiler scalarizes these
    // constant-index loads into s_load). Class 0 is always present.
    unsigned present = 1u;
#pragma unroll
    for (int i = 0; i < 12; ++i) present |= (1u << cfb[i]);

    const int g    = blockIdx.x * 256 + threadIdx.x;
    const int base = g * 4;             // 4 consecutive positions per thread
    float acc = 0.0f;                   // accumulates +ce of contributing positions

    if (base < kN) {
        // one coalesced 16B load of 4 targets
        const int4 t4 = reinterpret_cast<const int4*>(target)[g];
        const int t[4] = { t4.x, t4.y, t4.z, t4.w };

        // kS % 4 == 0, so a 4-group never crosses the batch boundary
        const int b  = (base >= kS) ? 1 : 0;
        const int s0 = base - b * kS;
        const float* __restrict__ plane = logit0 + (size_t)b * kC * kS + s0;

#pragma unroll
        for (int j = 0; j < 4; ++j) {
            const int tj = t[j];
            if ((present >> tj) & 1u) {           // alpha == 1
                float v = plane[(size_t)tj * kS + j];
                if (tj == 0) {
                    // class 0 absorbs the absent-class mass
#pragma unroll
                    for (int c = 1; c < kC; ++c)
                        if (!((present >> c) & 1u))
                            v += plane[(size_t)c * kS + j];
                }
                v = fminf(fmaxf(v, kSmooth), 1.0f);
                acc += __logf(v) + kSmooth;        // ce = logpt + SMOOTH
            }
            // alpha == 0 -> contributes exactly 0, no load issued
        }
    }

    // wave-64 butterfly reduce
#pragma unroll
    for (int off = 32; off > 0; off >>= 1)
        acc += __shfl_down(acc, off, 64);

    __shared__ float wave_sums[4];
    const int lane = threadIdx.x & 63;
    const int wid  = threadIdx.x >> 6;
    if (lane == 0) wave_sums[wid] = acc;
    __syncthreads();

    if (threadIdx.x == 0) {
        float s = wave_sums[0] + wave_sums[1] + wave_sums[2] + wave_sums[3];
        // loss = mean(-alpha * ce) = -(sum of ce) / N
        atomicAdd(out, s * (-1.0f / (float)kN));
    }
}

extern "C" void kernel_launch(void* const* d_in, const int* in_sizes, int n_in,
                              void* d_out, int out_size, void* d_ws, size_t ws_size,
                              hipStream_t stream)
{
    const float* logit0 = (const float*)d_in[0];
    const int*   target = (const int*)d_in[1];
    const int*   cfb    = (const int*)d_in[2];
    float*       out    = (float*)d_out;

    init_out_kernel<<<1, 1, 0, stream>>>(out);

    constexpr int threads = 256;
    constexpr int total_threads = kN / 4;                       // 442368
    constexpr int blocks = (total_threads + threads - 1) / threads;  // 1728
    mce_kernel<<<blocks, threads, 0, stream>>>(logit0, target, cfb, out);
}

// Round 2
// 233.359 us; speedup vs baseline: 1.1149x; 1.1149x over previous
//
#include <hip/hip_runtime.h>

// Problem constants (fixed by setup_inputs): B=2, C=24, D=H=W=96.
static constexpr int   kS = 96 * 96 * 96;   // 884736 spatial positions per batch
static constexpr int   kC = 24;
static constexpr int   kB = 2;
static constexpr int   kN = kB * kS;        // 1769472 total positions
static constexpr float kSmooth = 1e-5f;

// d_out is re-poisoned to 0xAA before every timed launch -> zero it ourselves.
__global__ void init_out_kernel(float* out) { out[0] = 0.0f; }

// Each thread: 4 consecutive positions. For each of the 24 class planes,
// one exec-masked coalesced float4 load (only fetched where needed).
// Sparsity: a plane's 16-float line is needed with prob 1-(23/24)^16 ~= 0.49,
// so expected HBM fetch ~= 0.49 * 170MB + 7MB (targets) ~= 91 MB.
__global__ __launch_bounds__(256) void mce_kernel(
    const float* __restrict__ logit0,
    const int*   __restrict__ target,
    const int*   __restrict__ cfb,      // class_for_batch, 12 ints
    float*       __restrict__ out)
{
    // Present-class bitmask (wave-uniform). Class 0 is always present.
    unsigned present = 1u;
#pragma unroll
    for (int i = 0; i < 12; ++i) present |= (1u << cfb[i]);

    const int g    = blockIdx.x * 256 + threadIdx.x;
    const int base = g * 4;             // 4 consecutive positions per thread

    // one coalesced 16B load of 4 targets
    const int4 t4 = reinterpret_cast<const int4*>(target)[g];
    const int t[4] = { t4.x, t4.y, t4.z, t4.w };

    // kS % 4 == 0, so a 4-group never crosses the batch boundary
    const int b  = (base >= kS) ? 1 : 0;
    const int s0 = base - b * kS;
    const float4* __restrict__ plane4 =
        reinterpret_cast<const float4*>(logit0 + (size_t)b * kC * kS + s0);

    const bool any0 = (t[0] == 0) | (t[1] == 0) | (t[2] == 0) | (t[3] == 0);

    // Phase 1: issue ALL guarded loads (independent -> stay outstanding,
    // single waitcnt before phase 2). Zero-init so unloaded lanes are clean.
    float4 x[kC];
#pragma unroll
    for (int c = 0; c < kC; ++c) {
        x[c] = make_float4(0.f, 0.f, 0.f, 0.f);
        const bool absent = !((present >> c) & 1u);
        const bool need = absent
            ? any0                                   // absent mass only matters where t==0
            : ((t[0] == c) | (t[1] == c) | (t[2] == c) | (t[3] == c));
        if (need) x[c] = plane4[(size_t)c * (kS / 4)];
    }

    // Phase 2: combine in registers.
    float acc = 0.0f;
#pragma unroll
    for (int j = 0; j < 4; ++j) {
        const int tj = t[j];
        float vj = 0.0f, asum = 0.0f;
#pragma unroll
        for (int c = 0; c < kC; ++c) {
            const float xc = (j == 0) ? x[c].x : (j == 1) ? x[c].y
                           : (j == 2) ? x[c].z : x[c].w;
            const bool absent = !((present >> c) & 1u);   // wave-uniform
            if (absent) asum += xc;                       // only used when tj==0
            else if (tj == c) vj = xc;                    // gather via select
        }
        float val = vj + ((tj == 0) ? asum : 0.0f);
        val = fminf(fmaxf(val, kSmooth), 1.0f);
        const float ce = __logf(val) + kSmooth;
        acc += (((present >> tj) & 1u) ? ce : 0.0f);      // alpha in {0,1}
    }

    // wave-64 butterfly reduce
#pragma unroll
    for (int off = 32; off > 0; off >>= 1)
        acc += __shfl_down(acc, off, 64);

    __shared__ float wave_sums[4];
    const int lane = threadIdx.x & 63;
    const int wid  = threadIdx.x >> 6;
    if (lane == 0) wave_sums[wid] = acc;
    __syncthreads();

    if (threadIdx.x == 0) {
        float s = wave_sums[0] + wave_sums[1] + wave_sums[2] + wave_sums[3];
        // loss = mean(-alpha * ce) = -(sum of ce) / N
        atomicAdd(out, s * (-1.0f / (float)kN));
    }
}

extern "C" void kernel_launch(void* const* d_in, const int* in_sizes, int n_in,
                              void* d_out, int out_size, void* d_ws, size_t ws_size,
                              hipStream_t stream)
{
    const float* logit0 = (const float*)d_in[0];
    const int*   target = (const int*)d_in[1];
    const int*   cfb    = (const int*)d_in[2];
    float*       out    = (float*)d_out;

    init_out_kernel<<<1, 1, 0, stream>>>(out);

    constexpr int threads = 256;
    constexpr int total_threads = kN / 4;                       // 442368
    constexpr int blocks = total_threads / threads;             // 1728
    mce_kernel<<<blocks, threads, 0, stream>>>(logit0, target, cfb, out);
}